// Round 10
// baseline (1567.312 us; speedup 1.0000x reference)
//
#include <hip/hip_runtime.h>

#define MAXB 400      // bucket slots (N=100000 -> 391 buckets of 256 nodes)
#define CAP2 9216     // fixed region entries per bucket (mean 8184, +11 sigma)
#define CSTAGE 32     // LDS staging entries per bucket in scatter
#define KB_BATCH 8192 // edges per block in scatter (391 blocks)

typedef __attribute__((ext_vector_type(8))) short bf16x8;
typedef __attribute__((ext_vector_type(4))) float f32x4;

// bf16 helpers
__device__ __forceinline__ unsigned int f2bf(float f) {
  unsigned int u = __float_as_uint(f);
  return (u + 0x7FFFu + ((u >> 16) & 1u)) >> 16;  // RNE
}
__device__ __forceinline__ float bf2f(unsigned short h) {
  return __uint_as_float(((unsigned int)h) << 16);
}
// packed-bf16 dword -> two floats
__device__ __forceinline__ float blo(unsigned int u) { return __uint_as_float(u << 16); }
__device__ __forceinline__ float bhi(unsigned int u) { return __uint_as_float(u & 0xFFFF0000u); }

// ---------------- init bucket cursors + one-time W -> bf16 convert ----------------
// grid = 64 blocks: must cover 64*256 W elements.
__global__ __launch_bounds__(256) void init_kernel(int* __restrict__ gcur, int nbkt,
                                                   const float* __restrict__ W,
                                                   unsigned short* __restrict__ wq) {
  int t = blockIdx.x * 256 + threadIdx.x;
  if (t < nbkt) gcur[t] = t * CAP2;
  if (t < 64 * 256) wq[t] = (unsigned short)f2bf(W[t]);
}

// ---------------- staged binned scatter into fixed bucket regions ----------------
// packed = (dst&255)<<24 | src   (src < 2^24)   [proven form]
__global__ __launch_bounds__(256) void scatter_kernel(const int* __restrict__ ei,
                                                      int* __restrict__ gcur,
                                                      unsigned int* __restrict__ ebuf,
                                                      int E, int nbkt) {
  __shared__ int lcnt[MAXB];
  __shared__ unsigned int lbuf[CSTAGE * MAXB];  // 51.2 KB, [slot][bucket]
  int t = threadIdx.x;
  for (int i = t; i < MAXB; i += 256) lcnt[i] = 0;
  __syncthreads();
  int base = blockIdx.x * KB_BATCH;
  int end = min(base + KB_BATCH, E);
  const int4* s4 = (const int4*)ei;
  const int4* d4 = (const int4*)(ei + E);
  for (int e = base + t * 4; e < end; e += 1024) {
    int4 sv = s4[e >> 2];
    int4 dv = d4[e >> 2];
#pragma unroll
    for (int j = 0; j < 4; ++j) {
      int src = (j == 0) ? sv.x : (j == 1) ? sv.y : (j == 2) ? sv.z : sv.w;
      int dst = (j == 0) ? dv.x : (j == 1) ? dv.y : (j == 2) ? dv.z : dv.w;
      int b = dst >> 8;
      unsigned int packed = ((unsigned int)(dst & 255) << 24) | (unsigned int)src;
      int slot = atomicAdd(&lcnt[b], 1);
      if (slot < CSTAGE) {
        lbuf[slot * MAXB + b] = packed;
      } else {  // rare spill
        int p = atomicAdd(&gcur[b], 1);
        if (p < (b + 1) * CAP2) ebuf[p] = packed;
      }
    }
  }
  __syncthreads();
  for (int b = t; b < nbkt; b += 256) {
    int n = lcnt[b];
    if (n > CSTAGE) n = CSTAGE;
    if (n > 0) {
      int p = atomicAdd(&gcur[b], n);
      if (p + n <= (b + 1) * CAP2)
        for (int i = 0; i < n; i++) ebuf[p + i] = lbuf[i * MAXB + b];
    }
  }
}

// ---------------- per-bucket degree histogram -> dinv (only output gemm needs) ----------------
// Non-returning LDS atomics; no scan, no re-sort, no col array.
__global__ __launch_bounds__(512) void deg_kernel(const unsigned int* __restrict__ ebuf,
                                                  const int* __restrict__ gcur,
                                                  float* __restrict__ dinv, int N) {
  __shared__ int lh[256];
  int b = blockIdx.x;
  int t = threadIdx.x;
  int e0 = b * CAP2;
  int cnt = gcur[b] - e0;
  if (cnt > CAP2) cnt = CAP2;
  if (t < 256) lh[t] = 0;
  __syncthreads();
  for (int i = t; i < cnt; i += 512) {
    atomicAdd(&lh[ebuf[e0 + i] >> 24], 1);
  }
  __syncthreads();
  if (t < 256) {
    int node = (b << 8) + t;
    if (node < N) dinv[node] = rsqrtf((float)lh[t] + 1.0f);
  }
}

// ---------------- xq = bf16(dinv * (x @ W^T)) : MFMA 16x16x32 bf16 ----------------
// 128 nodes/block (2 groups of 64), W pre-converted to bf16 (pure 32KB copy staging).
__global__ __launch_bounds__(256) void gemm_kernel(const float* __restrict__ x,
                                                   const unsigned short* __restrict__ wq,
                                                   const float* __restrict__ dinv,
                                                   unsigned short* __restrict__ xq,
                                                   int N) {
  __shared__ unsigned short wt[64 * 264];  // 33 KB, row stride 264 bf16
  int tid = threadIdx.x;

  {
    int c = tid >> 2;
    int kb = (tid & 3) << 6;
    const uint4* Wsrc = (const uint4*)(wq + (c << 8) + kb);
    uint4* Wdst = (uint4*)&wt[c * 264 + kb];
#pragma unroll
    for (int i = 0; i < 8; ++i) Wdst[i] = Wsrc[i];
  }
  __syncthreads();

  int lane = tid & 63;
  int q = lane >> 4;      // quad 0..3
  int m = lane & 15;      // A row / B col within tile
  int wv = tid >> 6;      // wave 0..3

#pragma unroll
  for (int g = 0; g < 2; ++g) {
    int n0 = (blockIdx.x << 7) + (g << 6) + (wv << 4);  // 16 nodes per wave-group
    int gn = n0 + m;
    if (gn >= N) gn = N - 1;  // clamp loads; stores masked below
    const float* xrow = x + ((size_t)gn << 8) + (q << 3);

    f32x4 acc0 = {0.f, 0.f, 0.f, 0.f};
    f32x4 acc1 = {0.f, 0.f, 0.f, 0.f};
    f32x4 acc2 = {0.f, 0.f, 0.f, 0.f};
    f32x4 acc3 = {0.f, 0.f, 0.f, 0.f};

#pragma unroll
    for (int ks = 0; ks < 8; ++ks) {
      float4 f0 = *(const float4*)(xrow + (ks << 5));
      float4 f1 = *(const float4*)(xrow + (ks << 5) + 4);
      bf16x8 a;
      a[0] = (short)f2bf(f0.x); a[1] = (short)f2bf(f0.y);
      a[2] = (short)f2bf(f0.z); a[3] = (short)f2bf(f0.w);
      a[4] = (short)f2bf(f1.x); a[5] = (short)f2bf(f1.y);
      a[6] = (short)f2bf(f1.z); a[7] = (short)f2bf(f1.w);
      int wo = (ks << 5) + (q << 3);
      bf16x8 b0 = *(const bf16x8*)&wt[(m)       * 264 + wo];
      bf16x8 b1 = *(const bf16x8*)&wt[(m + 16)  * 264 + wo];
      bf16x8 b2 = *(const bf16x8*)&wt[(m + 32)  * 264 + wo];
      bf16x8 b3 = *(const bf16x8*)&wt[(m + 48)  * 264 + wo];
      acc0 = __builtin_amdgcn_mfma_f32_16x16x32_bf16(a, b0, acc0, 0, 0, 0);
      acc1 = __builtin_amdgcn_mfma_f32_16x16x32_bf16(a, b1, acc1, 0, 0, 0);
      acc2 = __builtin_amdgcn_mfma_f32_16x16x32_bf16(a, b2, acc2, 0, 0, 0);
      acc3 = __builtin_amdgcn_mfma_f32_16x16x32_bf16(a, b3, acc3, 0, 0, 0);
    }

#pragma unroll
    for (int r = 0; r < 4; ++r) {
      int node = n0 + (q << 2) + r;
      if (node < N) {
        float di = dinv[node];
        size_t base = ((size_t)node << 6) + m;
        xq[base]      = (unsigned short)f2bf(acc0[r] * di);
        xq[base + 16] = (unsigned short)f2bf(acc1[r] * di);
        xq[base + 32] = (unsigned short)f2bf(acc2[r] * di);
        xq[base + 48] = (unsigned short)f2bf(acc3[r] * di);
      }
    }
  }
}

// ---------------- bucket aggregate: dense LDS accumulator + fused log_softmax ----------------
// One block per bucket of 256 nodes. acc[256][64] f32 = 64 KB LDS. Scans the bucket's
// UNSORTED ebuf entries once: per entry, the wave loads the source row (lane=class,
// 2B/lane = one 128B line) and ds_add_f32 into acc[dst&255][lane] (2-way bank alias =
// free). No per-node CSR needed at all. Epilogue: self-loop + dinv + bias + softmax.
__global__ __launch_bounds__(512) void agg_kernel(const unsigned short* __restrict__ xq,
                                                  const float* __restrict__ dinv,
                                                  const unsigned int* __restrict__ ebuf,
                                                  const int* __restrict__ gcur,
                                                  const float* __restrict__ bias,
                                                  float* __restrict__ out, int N) {
  __shared__ float acc[256 * 64];  // 64 KB exactly
  int b = blockIdx.x;
  int t = threadIdx.x;
  int lane = t & 63;
  int wv = t >> 6;  // 8 waves
  int e0 = b * CAP2;
  int cnt = gcur[b] - e0;
  if (cnt > CAP2) cnt = CAP2;

  // zero acc (float4 stores, conflict-free)
  {
    float4 z = {0.f, 0.f, 0.f, 0.f};
    for (int i = t; i < 256 * 16; i += 512) *(float4*)&acc[i << 2] = z;
  }
  __syncthreads();

  const unsigned int* ep = ebuf + e0;
  // units of 8 entries, unit u owned by wave (u&7); entry indices 8u are 32B-aligned.
  for (int u = wv;; u += 8) {
    int i = u << 3;
    if (i + 8 > cnt) {
      // at most one wave owns the partial tail
      for (; i < cnt; ++i) {
        unsigned int p = ep[i];
        float v = bf2f(xq[((size_t)(p & 0xFFFFFFu) << 6) + lane]);
        atomicAdd(&acc[((p >> 24) << 6) + lane], v);
      }
      break;
    }
    uint4 ua = *(const uint4*)(ep + i);
    uint4 ub = *(const uint4*)(ep + i + 4);
    // issue all 8 row loads first (MLP), then convert+accumulate
    unsigned short h0 = xq[((size_t)(ua.x & 0xFFFFFFu) << 6) + lane];
    unsigned short h1 = xq[((size_t)(ua.y & 0xFFFFFFu) << 6) + lane];
    unsigned short h2 = xq[((size_t)(ua.z & 0xFFFFFFu) << 6) + lane];
    unsigned short h3 = xq[((size_t)(ua.w & 0xFFFFFFu) << 6) + lane];
    unsigned short h4 = xq[((size_t)(ub.x & 0xFFFFFFu) << 6) + lane];
    unsigned short h5 = xq[((size_t)(ub.y & 0xFFFFFFu) << 6) + lane];
    unsigned short h6 = xq[((size_t)(ub.z & 0xFFFFFFu) << 6) + lane];
    unsigned short h7 = xq[((size_t)(ub.w & 0xFFFFFFu) << 6) + lane];
    atomicAdd(&acc[((ua.x >> 24) << 6) + lane], bf2f(h0));
    atomicAdd(&acc[((ua.y >> 24) << 6) + lane], bf2f(h1));
    atomicAdd(&acc[((ua.z >> 24) << 6) + lane], bf2f(h2));
    atomicAdd(&acc[((ua.w >> 24) << 6) + lane], bf2f(h3));
    atomicAdd(&acc[((ub.x >> 24) << 6) + lane], bf2f(h4));
    atomicAdd(&acc[((ub.y >> 24) << 6) + lane], bf2f(h5));
    atomicAdd(&acc[((ub.z >> 24) << 6) + lane], bf2f(h6));
    atomicAdd(&acc[((ub.w >> 24) << 6) + lane], bf2f(h7));
  }
  __syncthreads();

  // epilogue: 4 passes x (8 waves x 8 nodes). Lane = (grp = lane>>3 -> node,
  // s = lane&7 -> class octet). Identical math to the proven agg epilogue.
  int grp = lane >> 3;
  int s = lane & 7;
#pragma unroll
  for (int p = 0; p < 4; ++p) {
    int r = (p << 6) + (wv << 3) + grp;
    int node = (b << 8) + r;
    bool valid = (node < N);
    int nc = valid ? node : N - 1;
    float di = dinv[nc];
    float4 A0 = *(float4*)&acc[(r << 6) + (s << 3)];
    float4 A1 = *(float4*)&acc[(r << 6) + (s << 3) + 4];
    uint4 sv = *(const uint4*)(xq + ((size_t)nc << 6) + (s << 3));  // self-loop row
    float a0 = A0.x + blo(sv.x), a1 = A0.y + bhi(sv.x);
    float a2 = A0.z + blo(sv.y), a3 = A0.w + bhi(sv.y);
    float a4 = A1.x + blo(sv.z), a5 = A1.y + bhi(sv.z);
    float a6 = A1.z + blo(sv.w), a7 = A1.w + bhi(sv.w);

    float4 b0 = *(const float4*)(bias + (s << 3));
    float4 b1 = *(const float4*)(bias + (s << 3) + 4);
    float v0 = fmaf(di, a0, b0.x), v1 = fmaf(di, a1, b0.y);
    float v2 = fmaf(di, a2, b0.z), v3 = fmaf(di, a3, b0.w);
    float v4 = fmaf(di, a4, b1.x), v5 = fmaf(di, a5, b1.y);
    float v6 = fmaf(di, a6, b1.z), v7 = fmaf(di, a7, b1.w);

    float m = fmaxf(fmaxf(fmaxf(v0, v1), fmaxf(v2, v3)),
                    fmaxf(fmaxf(v4, v5), fmaxf(v6, v7)));
    m = fmaxf(m, __shfl_xor(m, 1, 64));
    m = fmaxf(m, __shfl_xor(m, 2, 64));
    m = fmaxf(m, __shfl_xor(m, 4, 64));
    float ssum = __expf(v0 - m) + __expf(v1 - m) + __expf(v2 - m) + __expf(v3 - m) +
                 __expf(v4 - m) + __expf(v5 - m) + __expf(v6 - m) + __expf(v7 - m);
    ssum += __shfl_xor(ssum, 1, 64);
    ssum += __shfl_xor(ssum, 2, 64);
    ssum += __shfl_xor(ssum, 4, 64);
    float lse = m + __logf(ssum);

    if (valid) {
      float* op = out + ((size_t)node << 6) + (s << 3);
      float4 w0, w1;
      w0.x = v0 - lse; w0.y = v1 - lse; w0.z = v2 - lse; w0.w = v3 - lse;
      w1.x = v4 - lse; w1.y = v5 - lse; w1.z = v6 - lse; w1.w = v7 - lse;
      *(float4*)op = w0;
      *(float4*)(op + 4) = w1;
    }
  }
}

extern "C" void kernel_launch(void* const* d_in, const int* in_sizes, int n_in,
                              void* d_out, int out_size, void* d_ws, size_t ws_size,
                              hipStream_t stream) {
  const float* x = (const float*)d_in[0];
  const int* ei = (const int*)d_in[1];
  const float* W = (const float*)d_in[2];
  const float* b = (const float*)d_in[3];
  float* out = (float*)d_out;

  const int N = in_sizes[0] / 256;  // 100000
  const int E = in_sizes[1] / 2;    // 3200000
  const int NBKT = (N + 255) >> 8;  // 391

  // workspace layout (col/rowstart/deg eliminated)
  char* ws = (char*)d_ws;
  size_t off = 0;
  unsigned short* xq = (unsigned short*)(ws + off); off += (size_t)N * 64 * sizeof(unsigned short);
  float* dinv = (float*)(ws + off);      off += (size_t)N * sizeof(float);
  unsigned int* ebuf = (unsigned int*)(ws + off); off += (size_t)NBKT * CAP2 * sizeof(unsigned int);
  int* gcur = (int*)(ws + off);          off += MAXB * sizeof(int);
  unsigned short* wq = (unsigned short*)(ws + off); off += 64 * 256 * sizeof(unsigned short);

  init_kernel<<<64, 256, 0, stream>>>(gcur, NBKT, W, wq);
  scatter_kernel<<<(E + KB_BATCH - 1) / KB_BATCH, 256, 0, stream>>>(ei, gcur, ebuf, E, NBKT);
  deg_kernel<<<NBKT, 512, 0, stream>>>(ebuf, gcur, dinv, N);
  gemm_kernel<<<(N + 127) / 128, 256, 0, stream>>>(x, wq, dinv, xq, N);
  agg_kernel<<<NBKT, 512, 0, stream>>>(xq, dinv, ebuf, gcur, b, out, N);
}

// Round 11
// 273.887 us; speedup vs baseline: 5.7225x; 5.7225x over previous
//
#include <hip/hip_runtime.h>

#define MAXB 400      // bucket slots (N=100000 -> 391 buckets of 256 nodes)
#define CAP2 9216     // fixed region entries per bucket (mean 8184, +11 sigma)
#define CSTAGE 32     // LDS staging entries per bucket in scatter
#define KB_BATCH 8192 // edges per block in scatter (391 blocks)
#define CAP 12288     // LDS col capacity per bucket in aggm

typedef __attribute__((ext_vector_type(8))) short bf16x8;
typedef __attribute__((ext_vector_type(4))) float f32x4;

// bf16 helpers
__device__ __forceinline__ unsigned int f2bf(float f) {
  unsigned int u = __float_as_uint(f);
  return (u + 0x7FFFu + ((u >> 16) & 1u)) >> 16;  // RNE
}
__device__ __forceinline__ float bf2f(unsigned short h) {
  return __uint_as_float(((unsigned int)h) << 16);
}
// packed-bf16 dword -> two floats
__device__ __forceinline__ float blo(unsigned int u) { return __uint_as_float(u << 16); }
__device__ __forceinline__ float bhi(unsigned int u) { return __uint_as_float(u & 0xFFFF0000u); }

// ---------------- init bucket cursors + one-time W -> bf16 convert ----------------
// grid = 64 blocks: must cover 64*256 W elements.
__global__ __launch_bounds__(256) void init_kernel(int* __restrict__ gcur, int nbkt,
                                                   const float* __restrict__ W,
                                                   unsigned short* __restrict__ wq) {
  int t = blockIdx.x * 256 + threadIdx.x;
  if (t < nbkt) gcur[t] = t * CAP2;
  if (t < 64 * 256) wq[t] = (unsigned short)f2bf(W[t]);
}

// ---------------- staged binned scatter into fixed bucket regions ----------------
// packed = (dst&255)<<24 | src   (src < 2^24)   [proven R6/R9 form]
__global__ __launch_bounds__(256) void scatter_kernel(const int* __restrict__ ei,
                                                      int* __restrict__ gcur,
                                                      unsigned int* __restrict__ ebuf,
                                                      int E, int nbkt) {
  __shared__ int lcnt[MAXB];
  __shared__ unsigned int lbuf[CSTAGE * MAXB];  // 51.2 KB, [slot][bucket]
  int t = threadIdx.x;
  for (int i = t; i < MAXB; i += 256) lcnt[i] = 0;
  __syncthreads();
  int base = blockIdx.x * KB_BATCH;
  int end = min(base + KB_BATCH, E);
  const int4* s4 = (const int4*)ei;
  const int4* d4 = (const int4*)(ei + E);
  for (int e = base + t * 4; e < end; e += 1024) {
    int4 sv = s4[e >> 2];
    int4 dv = d4[e >> 2];
#pragma unroll
    for (int j = 0; j < 4; ++j) {
      int src = (j == 0) ? sv.x : (j == 1) ? sv.y : (j == 2) ? sv.z : sv.w;
      int dst = (j == 0) ? dv.x : (j == 1) ? dv.y : (j == 2) ? dv.z : dv.w;
      int b = dst >> 8;
      unsigned int packed = ((unsigned int)(dst & 255) << 24) | (unsigned int)src;
      int slot = atomicAdd(&lcnt[b], 1);
      if (slot < CSTAGE) {
        lbuf[slot * MAXB + b] = packed;
      } else {  // rare spill
        int p = atomicAdd(&gcur[b], 1);
        if (p < (b + 1) * CAP2) ebuf[p] = packed;
      }
    }
  }
  __syncthreads();
  for (int b = t; b < nbkt; b += 256) {
    int n = lcnt[b];
    if (n > CSTAGE) n = CSTAGE;
    if (n > 0) {
      int p = atomicAdd(&gcur[b], n);
      if (p + n <= (b + 1) * CAP2)
        for (int i = 0; i < n; i++) ebuf[p + i] = lbuf[i * MAXB + b];
    }
  }
}

// ---------------- per-bucket degree histogram -> dinv (gemm's only dependency) ----------------
__global__ __launch_bounds__(512) void deg_kernel(const unsigned int* __restrict__ ebuf,
                                                  const int* __restrict__ gcur,
                                                  float* __restrict__ dinv, int N) {
  __shared__ int lh[256];
  int b = blockIdx.x;
  int t = threadIdx.x;
  int e0 = b * CAP2;
  int cnt = gcur[b] - e0;
  if (cnt > CAP2) cnt = CAP2;
  if (t < 256) lh[t] = 0;
  __syncthreads();
  for (int i = t; i < cnt; i += 512) {
    atomicAdd(&lh[ebuf[e0 + i] >> 24], 1);
  }
  __syncthreads();
  if (t < 256) {
    int node = (b << 8) + t;
    if (node < N) dinv[node] = rsqrtf((float)lh[t] + 1.0f);
  }
}

// ---------------- xq = bf16(dinv * (x @ W^T)) : MFMA 16x16x32 bf16 ----------------
// 128 nodes/block (2 groups of 64), W pre-converted to bf16 (pure 32KB copy staging).
__global__ __launch_bounds__(256) void gemm_kernel(const float* __restrict__ x,
                                                   const unsigned short* __restrict__ wq,
                                                   const float* __restrict__ dinv,
                                                   unsigned short* __restrict__ xq,
                                                   int N) {
  __shared__ unsigned short wt[64 * 264];  // 33 KB, row stride 264 bf16
  int tid = threadIdx.x;

  {
    int c = tid >> 2;
    int kb = (tid & 3) << 6;
    const uint4* Wsrc = (const uint4*)(wq + (c << 8) + kb);
    uint4* Wdst = (uint4*)&wt[c * 264 + kb];
#pragma unroll
    for (int i = 0; i < 8; ++i) Wdst[i] = Wsrc[i];
  }
  __syncthreads();

  int lane = tid & 63;
  int q = lane >> 4;      // quad 0..3
  int m = lane & 15;      // A row / B col within tile
  int wv = tid >> 6;      // wave 0..3

#pragma unroll
  for (int g = 0; g < 2; ++g) {
    int n0 = (blockIdx.x << 7) + (g << 6) + (wv << 4);  // 16 nodes per wave-group
    int gn = n0 + m;
    if (gn >= N) gn = N - 1;  // clamp loads; stores masked below
    const float* xrow = x + ((size_t)gn << 8) + (q << 3);

    f32x4 acc0 = {0.f, 0.f, 0.f, 0.f};
    f32x4 acc1 = {0.f, 0.f, 0.f, 0.f};
    f32x4 acc2 = {0.f, 0.f, 0.f, 0.f};
    f32x4 acc3 = {0.f, 0.f, 0.f, 0.f};

#pragma unroll
    for (int ks = 0; ks < 8; ++ks) {
      float4 f0 = *(const float4*)(xrow + (ks << 5));
      float4 f1 = *(const float4*)(xrow + (ks << 5) + 4);
      bf16x8 a;
      a[0] = (short)f2bf(f0.x); a[1] = (short)f2bf(f0.y);
      a[2] = (short)f2bf(f0.z); a[3] = (short)f2bf(f0.w);
      a[4] = (short)f2bf(f1.x); a[5] = (short)f2bf(f1.y);
      a[6] = (short)f2bf(f1.z); a[7] = (short)f2bf(f1.w);
      int wo = (ks << 5) + (q << 3);
      bf16x8 b0 = *(const bf16x8*)&wt[(m)       * 264 + wo];
      bf16x8 b1 = *(const bf16x8*)&wt[(m + 16)  * 264 + wo];
      bf16x8 b2 = *(const bf16x8*)&wt[(m + 32)  * 264 + wo];
      bf16x8 b3 = *(const bf16x8*)&wt[(m + 48)  * 264 + wo];
      acc0 = __builtin_amdgcn_mfma_f32_16x16x32_bf16(a, b0, acc0, 0, 0, 0);
      acc1 = __builtin_amdgcn_mfma_f32_16x16x32_bf16(a, b1, acc1, 0, 0, 0);
      acc2 = __builtin_amdgcn_mfma_f32_16x16x32_bf16(a, b2, acc2, 0, 0, 0);
      acc3 = __builtin_amdgcn_mfma_f32_16x16x32_bf16(a, b3, acc3, 0, 0, 0);
    }

#pragma unroll
    for (int r = 0; r < 4; ++r) {
      int node = n0 + (q << 2) + r;
      if (node < N) {
        float di = dinv[node];
        size_t base = ((size_t)node << 6) + m;
        xq[base]      = (unsigned short)f2bf(acc0[r] * di);
        xq[base + 16] = (unsigned short)f2bf(acc1[r] * di);
        xq[base + 32] = (unsigned short)f2bf(acc2[r] * di);
        xq[base + 48] = (unsigned short)f2bf(acc3[r] * di);
      }
    }
  }
}

// ---------------- merged CSR-build + pull-aggregate + log_softmax ----------------
// One block (1024 thr, 16 waves) per bucket. Phase A: build per-node col lists in LDS
// (histogram -> shuffle scan -> re-scatter into lcol) — the proven csr phases, but the
// 12.8MB col array never touches global memory. Phase B: the proven R6 agg body
// (8 nodes/wave, uint4 16B/lane wide gather, 4-wide unroll) reading cols from LDS.
// deg/dinv come free from the LDS cursors: d = lh[r]-lex[r], di = rsqrt(d+1).
__global__ __launch_bounds__(1024) void aggm_kernel(const unsigned short* __restrict__ xq,
                                                    const unsigned int* __restrict__ ebuf,
                                                    const int* __restrict__ gcur,
                                                    const float* __restrict__ bias,
                                                    float* __restrict__ out, int N) {
  __shared__ int lh[256];     // histogram -> cursor -> end-cursor
  __shared__ int lex[256];    // exclusive starts
  __shared__ int lcol[CAP];   // 48 KB
  __shared__ int wbase[4];
  int b = blockIdx.x;
  int t = threadIdx.x;
  int e0 = b * CAP2;
  int cnt = gcur[b] - e0;
  if (cnt > CAP2) cnt = CAP2;

  if (t < 256) lh[t] = 0;
  __syncthreads();
  for (int i = t; i < cnt; i += 1024) {
    atomicAdd(&lh[ebuf[e0 + i] >> 24], 1);
  }
  __syncthreads();
  int v = 0, incl = 0;
  if (t < 256) {
    v = lh[t];
    int ln = t & 63;
    incl = v;
#pragma unroll
    for (int off = 1; off < 64; off <<= 1) {
      int sh = __shfl_up(incl, off, 64);
      if (ln >= off) incl += sh;
    }
    if (ln == 63) wbase[t >> 6] = incl;
  }
  __syncthreads();
  if (t == 0) {
    int s = 0;
#pragma unroll
    for (int i = 0; i < 4; ++i) { int tv = wbase[i]; wbase[i] = s; s += tv; }
  }
  __syncthreads();
  if (t < 256) {
    int excl = wbase[t >> 6] + incl - v;
    lex[t] = excl;
    lh[t] = excl;  // running cursor
  }
  __syncthreads();
  for (int i = t; i < cnt; i += 1024) {
    unsigned int p = ebuf[e0 + i];
    int pos = atomicAdd(&lh[p >> 24], 1);
    if (pos < CAP) lcol[pos] = (int)(p & 0xFFFFFFu);
  }
  __syncthreads();
  // lh[r] is now the END cursor; deg = lh[r] - lex[r].

  // Phase B: gather. 16 waves x 8 nodes x 2 passes = 256 nodes.
  int lane = t & 63;
  int wv = t >> 6;
  int grp = lane >> 3;  // node slot within wave
  int s = lane & 7;     // class octet
  const unsigned short* xqs = xq + (s << 3);

#pragma unroll
  for (int p = 0; p < 2; ++p) {
    int r = (p << 7) + (wv << 3) + grp;  // 0..255
    int node = (b << 8) + r;
    bool valid = (node < N);
    int nc = valid ? node : N - 1;
    int st = lex[r];
    int d = lh[r] - st;
    float di = rsqrtf((float)d + 1.0f);
    const int* cp = lcol + st;

    // self-loop row: issue early
    uint4 sv = *(const uint4*)(xqs + ((size_t)nc << 6));

    float a0 = 0.f, a1 = 0.f, a2 = 0.f, a3 = 0.f;
    float a4 = 0.f, a5 = 0.f, a6 = 0.f, a7 = 0.f;

    int i = 0;
    int c0 = 0, c1 = 0, c2 = 0, c3 = 0;
    if (i + 4 <= d) { c0 = cp[0]; c1 = cp[1]; c2 = cp[2]; c3 = cp[3]; }
    while (i + 4 <= d) {
      uint4 v0 = *(const uint4*)(xqs + ((size_t)(unsigned)c0 << 6));
      uint4 v1 = *(const uint4*)(xqs + ((size_t)(unsigned)c1 << 6));
      uint4 v2 = *(const uint4*)(xqs + ((size_t)(unsigned)c2 << 6));
      uint4 v3 = *(const uint4*)(xqs + ((size_t)(unsigned)c3 << 6));
      i += 4;
      if (i + 4 <= d) { c0 = cp[i]; c1 = cp[i + 1]; c2 = cp[i + 2]; c3 = cp[i + 3]; }
      a0 += blo(v0.x); a1 += bhi(v0.x); a2 += blo(v0.y); a3 += bhi(v0.y);
      a4 += blo(v0.z); a5 += bhi(v0.z); a6 += blo(v0.w); a7 += bhi(v0.w);
      a0 += blo(v1.x); a1 += bhi(v1.x); a2 += blo(v1.y); a3 += bhi(v1.y);
      a4 += blo(v1.z); a5 += bhi(v1.z); a6 += blo(v1.w); a7 += bhi(v1.w);
      a0 += blo(v2.x); a1 += bhi(v2.x); a2 += blo(v2.y); a3 += bhi(v2.y);
      a4 += blo(v2.z); a5 += bhi(v2.z); a6 += blo(v2.w); a7 += bhi(v2.w);
      a0 += blo(v3.x); a1 += bhi(v3.x); a2 += blo(v3.y); a3 += bhi(v3.y);
      a4 += blo(v3.z); a5 += bhi(v3.z); a6 += blo(v3.w); a7 += bhi(v3.w);
    }
    for (; i < d; ++i) {
      int c = cp[i];
      uint4 vx = *(const uint4*)(xqs + ((size_t)(unsigned)c << 6));
      a0 += blo(vx.x); a1 += bhi(vx.x); a2 += blo(vx.y); a3 += bhi(vx.y);
      a4 += blo(vx.z); a5 += bhi(vx.z); a6 += blo(vx.w); a7 += bhi(vx.w);
    }
    // self-loop term
    a0 += blo(sv.x); a1 += bhi(sv.x); a2 += blo(sv.y); a3 += bhi(sv.y);
    a4 += blo(sv.z); a5 += bhi(sv.z); a6 += blo(sv.w); a7 += bhi(sv.w);

    float4 b0 = *(const float4*)(bias + (s << 3));
    float4 b1 = *(const float4*)(bias + (s << 3) + 4);
    float v0 = fmaf(di, a0, b0.x), v1 = fmaf(di, a1, b0.y);
    float v2 = fmaf(di, a2, b0.z), v3 = fmaf(di, a3, b0.w);
    float v4 = fmaf(di, a4, b1.x), v5 = fmaf(di, a5, b1.y);
    float v6 = fmaf(di, a6, b1.z), v7 = fmaf(di, a7, b1.w);

    float m = fmaxf(fmaxf(fmaxf(v0, v1), fmaxf(v2, v3)),
                    fmaxf(fmaxf(v4, v5), fmaxf(v6, v7)));
    m = fmaxf(m, __shfl_xor(m, 1, 64));
    m = fmaxf(m, __shfl_xor(m, 2, 64));
    m = fmaxf(m, __shfl_xor(m, 4, 64));
    float ssum = __expf(v0 - m) + __expf(v1 - m) + __expf(v2 - m) + __expf(v3 - m) +
                 __expf(v4 - m) + __expf(v5 - m) + __expf(v6 - m) + __expf(v7 - m);
    ssum += __shfl_xor(ssum, 1, 64);
    ssum += __shfl_xor(ssum, 2, 64);
    ssum += __shfl_xor(ssum, 4, 64);
    float lse = m + __logf(ssum);

    if (valid) {
      float* op = out + ((size_t)node << 6) + (s << 3);
      float4 w0, w1;
      w0.x = v0 - lse; w0.y = v1 - lse; w0.z = v2 - lse; w0.w = v3 - lse;
      w1.x = v4 - lse; w1.y = v5 - lse; w1.z = v6 - lse; w1.w = v7 - lse;
      *(float4*)op = w0;
      *(float4*)(op + 4) = w1;
    }
  }
}

extern "C" void kernel_launch(void* const* d_in, const int* in_sizes, int n_in,
                              void* d_out, int out_size, void* d_ws, size_t ws_size,
                              hipStream_t stream) {
  const float* x = (const float*)d_in[0];
  const int* ei = (const int*)d_in[1];
  const float* W = (const float*)d_in[2];
  const float* b = (const float*)d_in[3];
  float* out = (float*)d_out;

  const int N = in_sizes[0] / 256;  // 100000
  const int E = in_sizes[1] / 2;    // 3200000
  const int NBKT = (N + 255) >> 8;  // 391

  // workspace layout (col/rowstart/deg arrays eliminated)
  char* ws = (char*)d_ws;
  size_t off = 0;
  unsigned short* xq = (unsigned short*)(ws + off); off += (size_t)N * 64 * sizeof(unsigned short);
  float* dinv = (float*)(ws + off);      off += (size_t)N * sizeof(float);
  unsigned int* ebuf = (unsigned int*)(ws + off); off += (size_t)NBKT * CAP2 * sizeof(unsigned int);
  int* gcur = (int*)(ws + off);          off += MAXB * sizeof(int);
  unsigned short* wq = (unsigned short*)(ws + off); off += 64 * 256 * sizeof(unsigned short);

  init_kernel<<<64, 256, 0, stream>>>(gcur, NBKT, W, wq);
  scatter_kernel<<<(E + KB_BATCH - 1) / KB_BATCH, 256, 0, stream>>>(ei, gcur, ebuf, E, NBKT);
  deg_kernel<<<NBKT, 512, 0, stream>>>(ebuf, gcur, dinv, N);
  gemm_kernel<<<(N + 127) / 128, 256, 0, stream>>>(x, wq, dinv, xq, N);
  aggm_kernel<<<NBKT, 1024, 0, stream>>>(xq, ebuf, gcur, b, out, N);
}